// Round 6
// baseline (112169.373 us; speedup 1.0000x reference)
//
#include <hip/hip_runtime.h>
#include <cstdint>
#include <cstddef>

// PlainRNN fused: h_{t+1} = tanh(h_t @ W_eff + b_eff), traj[t] = h_t @ W_h2o + b_h2o
// W_eff = W_h2h + W_h2o @ W_i2h  (recurrence composition removes x from the loop)
//
// Persistent kernel: 16 groups (16 batch rows each) x 16 blocks (72 of 1152 cols).
// Groups formed DYNAMICALLY per-XCD (HW_REG_XCC_ID + per-XCD slot counter):
// all 16 members share one XCD L2 BY CONSTRUCTION.
//
// R11 = R7 skeleton, with the flag transport localized to the XCD L2.
//   Ledger: R5 1600 (atomicAdd+poll) | R6 3667 (poll flood: agent polls hit the
//   MALL; FETCH +10.7MB) | R7 1452 (BEST: store-flag + wave0 throttled poll) |
//   R8 94ms (sc0 poll never saw the flag) | R9 2251 (chain-multiplex = C x body
//   serialization) | R10 3542 (4x pollers + 64 agent flag stores re-flooded the
//   fabric: FETCH +10MB, WRITE +12.3MB == R6's exact signature).
//   Synthesis: agent-scope flag ops (stores AND loads) are serviced at the
//   memory-side coherence point => every hop is a fabric RT => R7's ~1.3us/step
//   sync is that mechanism's floor. Meanwhile plain stores DO reach the XCD L2
//   (h-path correct every round); R8's sc0 poll failed because a hot poll loop
//   PINS its own L1 line (never evicted => stale forever), while h-loads work
//   via guaranteed capacity eviction (512KB streamed between touches).
//   R11: poll round = buffer_inv (vL1 invalidate; compiler emits it for fences
//   on this target, so it assembles) -> s_waitcnt -> plain global_load. The
//   load must miss L1 and read the XCD L2 where the producer's write-through
//   plain store landed. Arrival = plain volatile store after the drain barrier
//   (vmcnt(0) drained => L2 order is h-then-flag). Both handshake sides are
//   XCD-local (~0.3us RT) instead of MALL RTs (~1.3us).
//   Everything else byte-identical to R7: wave0-only poll + s_sleep(1) backoff
//   (poller count is the traffic knob - R10), 16 flags on one 128B line, three
//   __syncthreads, pass1 (hidden, consumed) / pass2 (y, unconsumed) split,
//   bown bias hoist, 4-slot hbuf rotation, plain h stores/loads.

#define BATCH  256
#define INPUT  128
#define HIDDEN 1024
#define OUTPUT 128
#define TSTEPS 512
#define NCAT   1152
#define NTILE  72
#define GROUPS 16
#define MEMB   16
#define NSLOT  4

// workspace layout (bytes)
#define WS_WFRAG 0u
#define WS_BEFF  2621440u
#define WS_HBUF  2629632u                 // 4 slots x 256x1024 f16 = 4x524288
#define WS_BAR   4726784u
// bar[] u32: [g*32 + mem]   per-member step flags (one 128B line per group)
//            [512 + xcc*32] per-XCD slot counters (one-time)
#define BAR_U32S 768

typedef _Float16 f16;
typedef _Float16 v8h __attribute__((ext_vector_type(8)));
typedef float    v4f __attribute__((ext_vector_type(4)));

__device__ __forceinline__ float fast_tanh(float x){
  float e = __expf(2.0f * x);
  return (e - 1.0f) / (e + 1.0f);
}

// Poll primitive: invalidate vL1, then plain-load the flag word.
// buffer_inv is vL1-only (no sc1 => no L2 writeback/inv, no fabric traffic).
// VMEM ops issue in order within a wave; the interleaved vmcnt(0) guarantees
// the invalidate completes before the load issues => the load misses L1 and is
// served by the XCD L2, where producers' write-through plain stores land.
__device__ __forceinline__ unsigned poll_flag_l2(const unsigned* p){
  unsigned v;
  asm volatile("buffer_inv\n\t"
               "s_waitcnt vmcnt(0)\n\t"
               "global_load_dword %0, %1, off\n\t"
               "s_waitcnt vmcnt(0)"
               : "=v"(v) : "v"(p) : "memory");
  return v;
}

// ---- bias composition
__global__ void k_bias(const float* __restrict__ bi2h, const float* __restrict__ bh2h,
                       const float* __restrict__ bh2o, const float* __restrict__ Wi2h,
                       float* __restrict__ beff){
  int n = blockIdx.x*256 + threadIdx.x;
  if (n >= 1168) return;
  float v = 0.f;
  if (n < HIDDEN){
    v = bi2h[n] + bh2h[n];
    for (int j=0;j<INPUT;j++) v += bh2o[j]*Wi2h[j*HIDDEN + n];
  } else if (n < NCAT){
    v = bh2o[n - HIDDEN];
  }
  beff[n] = v;
}

// ---- h_1 = tanh(x0 @ W_i2h + b_i2h + b_h2h) -> slot 0
__global__ void k_h1(const float* __restrict__ x0, const float* __restrict__ Wi2h,
                     const float* __restrict__ bi2h, const float* __restrict__ bh2h,
                     f16* __restrict__ hbuf){
  int idx = blockIdx.x*256 + threadIdx.x;
  int m = idx >> 10, n = idx & 1023;
  float acc = bi2h[n] + bh2h[n];
  const float* xr = x0 + m*INPUT;
  for (int j=0;j<INPUT;j++) acc += xr[j]*Wi2h[j*HIDDEN + n];
  hbuf[idx] = (f16)fast_tanh(acc);
}

// ---- traj[0] = x_0
__global__ void k_copy0(const float* __restrict__ x0, float* __restrict__ out){
  int i = blockIdx.x*256 + threadIdx.x;
  out[i] = x0[i];
}

// ---- W fragment packing: [mem 16][wave 4][kk 8][c 5][lane 64][8 halves]
__global__ void k_wfrag(const float* __restrict__ Wh2h, const float* __restrict__ Wh2o,
                        const float* __restrict__ Wi2h, f16* __restrict__ Wfrag){
  int gid = blockIdx.x*256 + threadIdx.x;
  int lane = gid & 63;
  int fi = gid >> 6;
  int c = fi % 5, kk = (fi/5) & 7, wv = (fi/40) & 3, mem = fi/160;
  int k0 = wv*256 + kk*32 + (lane>>4)*8;
  int n  = mem*NTILE + c*16 + (lane & 15);
  f16 vals[8];
  if (n >= NCAT){
    #pragma unroll
    for (int j=0;j<8;j++) vals[j] = (f16)0.f;
  } else if (n >= HIDDEN){
    #pragma unroll
    for (int j=0;j<8;j++) vals[j] = (f16)Wh2o[(k0+j)*OUTPUT + (n-HIDDEN)];
  } else {
    float acc[8];
    #pragma unroll
    for (int j=0;j<8;j++) acc[j] = Wh2h[(k0+j)*HIDDEN + n];
    for (int q=0;q<INPUT;q++){
      float wi = Wi2h[q*HIDDEN + n];
      #pragma unroll
      for (int j=0;j<8;j++) acc[j] += Wh2o[(k0+j)*OUTPUT + q]*wi;
    }
    #pragma unroll
    for (int j=0;j<8;j++) vals[j] = (f16)acc[j];
  }
  v8h pack;
  #pragma unroll
  for (int j=0;j<8;j++) pack[j] = vals[j];
  *(v8h*)(Wfrag + (size_t)gid*8) = pack;
}

// ---- persistent recurrence kernel: 256 blocks x 256 threads, 1 block/CU (96KB dyn LDS)
__global__ void __launch_bounds__(256, 1)
k_rnn(const f16* __restrict__ Wfrag, const float* __restrict__ beff,
      f16* __restrict__ hbuf, unsigned int* __restrict__ bar,
      float* __restrict__ out){
  extern __shared__ char lds_raw[];
  float*    red    = (float*)lds_raw;              // [(c*3+rank)][lane][4] f32, 15360 B
  unsigned* s_slot = (unsigned*)(lds_raw + 16384);

  const int tid  = threadIdx.x;
  const int lane = tid & 63;
  const int wv   = tid >> 6;

  // Dynamic same-XCD group formation. 1 block/CU + grid==CU count => 32 blocks/XCD.
  // Group = xcc*2 + slot/16, member = slot%16: group shares one XCD L2 BY CONSTRUCTION.
  if (tid == 0){
    unsigned xcc;
    asm volatile("s_getreg_b32 %0, hwreg(HW_REG_XCC_ID)" : "=s"(xcc));
    xcc &= 7;
    unsigned slot = atomicAdd(&bar[512 + xcc*32], 1u);  // one-time, device-scope
    *s_slot = xcc*32 + (slot & 31u);
  }
  __syncthreads();
  const unsigned sid = *s_slot;
  const int g   = sid >> 4;
  const int mem = sid & 15;
  if (g >= GROUPS) return;
  const int m0   = g * 16;
  const int n0   = mem * NTILE;
  const int quad = lane >> 4;
  const int l15  = lane & 15;

  // B fragments resident in registers for the whole 511-step loop
  v8h bw[8][5];
  {
    const f16* wp = Wfrag + ((size_t)((mem*4 + wv)*40)*64 + lane)*8;
    #pragma unroll
    for (int kk=0;kk<8;kk++)
      #pragma unroll
      for (int c=0;c<5;c++)
        bw[kk][c] = *(const v8h*)(wp + (size_t)((kk*5+c)*64)*8);
  }

  // Per-thread bias for owned columns hoisted into registers (the per-step
  // beff[col] load always missed L1 — A-stream evicts it — and sat on the
  // post-reduce critical path). wv owns tiles c where c&3==wv.
  float bown[2] = {0.f, 0.f};
  #pragma unroll
  for (int c=0;c<5;c++){
    if ((c & 3) == wv){
      int colT = c*16 + l15;
      int col  = n0 + colT;
      if (colT < NTILE && col < NCAT) bown[c>>2] = beff[col];
    }
  }

  const int kbase = wv*256;
  unsigned int* flg = bar + g*32;   // 16 per-member flags, one 128B line per group

  for (int t=1; t<TSTEPS; ++t){
    // ---- wait: all 16 member flags >= t-1. Wave 0 ONLY (poller count is the
    // traffic knob — R6/R10): lanes poll flg[lane&15] via buffer_inv + plain
    // load (XCD-L2-served, no fabric trip), s_sleep(1) backoff.
    // Bounded: if the mechanism is broken we degrade to the tries-timeout
    // (visible in dur), and correctness still holds — never a hang.
    if (wv == 0){
      const unsigned target = (unsigned)(t-1);
      const unsigned* fp = flg + (lane & 15);
      unsigned tries = 0;
      for (;;){
        unsigned f = poll_flag_l2(fp);
        if (__all((int)(f >= target))) break;
        if (++tries > 2048u) break;
        __builtin_amdgcn_s_sleep(1);
      }
    }
    __syncthreads();   // release: waves 1-3 park here while wave 0 polls

    const f16* hin  = hbuf + (size_t)((t-1)&(NSLOT-1))*(BATCH*HIDDEN);
    f16*       hout = hbuf + (size_t)(t&(NSLOT-1))*(BATCH*HIDDEN);

    // A fragments: plain vector loads. 4-slot rotation guarantees the L1 line
    // for this address was evicted (128KB/step streamed) => miss L1, hit the
    // shared XCD L2 (always fresh). lane holds A[m=lane&15][k=quad*8+j].
    v8h af[8];
    {
      const v8h* abase = (const v8h*)(hin + (size_t)(m0 + l15)*HIDDEN + kbase + quad*8);
      #pragma unroll
      for (int kk=0;kk<8;kk++)
        af[kk] = abase[kk*4];            // stride 32 halves = 4 v8h
    }

    v4f acc[5];
    #pragma unroll
    for (int c=0;c<5;c++){ v4f z = {0.f,0.f,0.f,0.f}; acc[c] = z; }

    #pragma unroll
    for (int kk=0;kk<8;kk++){
      #pragma unroll
      for (int c=0;c<5;c++)
        acc[c] = __builtin_amdgcn_mfma_f32_16x16x32_f16(af[kk], bw[kk][c], acc[c], 0,0,0);
    }

    // cross-wave K reduction via LDS. tile c owner = c&3.
    #pragma unroll
    for (int c=0;c<5;c++){
      int owner = c & 3;
      if (wv != owner){
        int rank = (wv > owner) ? wv-1 : wv;
        *(v4f*)(red + ((size_t)(c*3 + rank)*64 + lane)*4) = acc[c];
      }
    }
    __syncthreads();   // reduce visibility

    // pass 1: hidden columns (consumed by the group next step) -> plain stores
    // into the XCD L2.
    #pragma unroll
    for (int c=0;c<5;c++){
      if ((c & 3) == wv){
        int colT = c*16 + l15;
        int col  = n0 + colT;
        if (col < HIDDEN && colT < NTILE){
          v4f s = acc[c];
          #pragma unroll
          for (int r=0;r<3;r++) s += *(const v4f*)(red + ((size_t)(c*3 + r)*64 + lane)*4);
          float b = bown[c>>2];
          #pragma unroll
          for (int r=0;r<4;r++){
            float v = fast_tanh(s[r] + b);
            hout[(size_t)(m0 + quad*4 + r)*HIDDEN + col] = (f16)v;  // C/D: col=lane&15,row=quad*4+r
          }
        }
      }
    }
    __syncthreads();   // drain: each wave waits vmcnt(0) => all h stores acked in L2

    // arrival: PLAIN volatile store (write-through vL1 -> XCD L2; the same
    // mechanism the h data provably uses). h-then-flag order guaranteed by the
    // drain barrier's vmcnt(0). Consumers see it via buffer_inv polls.
    if (tid == 0)
      *(volatile unsigned*)(flg + mem) = (unsigned)t;

    // pass 2: y columns (consumed by nobody) — off the critical path, overlaps
    // group-mates' polling. red stable until next step's post-release writes.
    #pragma unroll
    for (int c=0;c<5;c++){
      if ((c & 3) == wv){
        int colT = c*16 + l15;
        int col  = n0 + colT;
        if (col >= HIDDEN && colT < NTILE){
          v4f s = acc[c];
          #pragma unroll
          for (int r=0;r<3;r++) s += *(const v4f*)(red + ((size_t)(c*3 + r)*64 + lane)*4);
          float b = bown[c>>2];
          float* op = out + (size_t)t*(BATCH*OUTPUT) + (col - HIDDEN);
          #pragma unroll
          for (int r=0;r<4;r++)
            op[(size_t)(m0 + quad*4 + r)*OUTPUT] = s[r] + b;
        }
      }
    }
  }
}

extern "C" void kernel_launch(void* const* d_in, const int* in_sizes, int n_in,
                              void* d_out, int out_size, void* d_ws, size_t ws_size,
                              hipStream_t stream){
  const float* x0   = (const float*)d_in[0];
  const float* Wi2h = (const float*)d_in[1];
  const float* bi2h = (const float*)d_in[2];
  const float* Wh2h = (const float*)d_in[3];
  const float* bh2h = (const float*)d_in[4];
  const float* Wh2o = (const float*)d_in[5];
  const float* bh2o = (const float*)d_in[6];
  float* out = (float*)d_out;
  char* ws = (char*)d_ws;

  f16*          Wfrag = (f16*)(ws + WS_WFRAG);
  float*        beff  = (float*)(ws + WS_BEFF);
  f16*          hbuf  = (f16*)(ws + WS_HBUF);
  unsigned int* bar   = (unsigned int*)(ws + WS_BAR);

  hipMemsetAsync(bar, 0, BAR_U32S*sizeof(unsigned int), stream);
  k_bias <<<5,    256, 0, stream>>>(bi2h, bh2h, bh2o, Wi2h, beff);
  k_h1   <<<1024, 256, 0, stream>>>(x0, Wi2h, bi2h, bh2h, hbuf);
  k_copy0<<<128,  256, 0, stream>>>(x0, out);
  k_wfrag<<<640,  256, 0, stream>>>(Wh2h, Wh2o, Wi2h, Wfrag);

  // 96KB dynamic LDS forces 1 block/CU -> all 256 blocks co-resident, 32 per XCD,
  // 1 wave/SIMD -> full VGPR budget for register-resident W fragments.
  hipFuncSetAttribute((const void*)k_rnn, hipFuncAttributeMaxDynamicSharedMemorySize, 98304);
  k_rnn<<<256, 256, 98304, stream>>>(Wfrag, beff, hbuf, bar, out);
}

// Round 7
// 1884.465 us; speedup vs baseline: 59.5232x; 59.5232x over previous
//
#include <hip/hip_runtime.h>
#include <cstdint>
#include <cstddef>

// PlainRNN fused: h_{t+1} = tanh(h_t @ W_eff + b_eff), traj[t] = h_t @ W_h2o + b_h2o
// W_eff = W_h2h + W_h2o @ W_i2h  (recurrence composition removes x from the loop)
//
// Persistent kernel: 16 groups (16 batch rows each) x 16 blocks (72 of 1152 cols).
// Groups formed DYNAMICALLY per-XCD (HW_REG_XCC_ID + per-XCD slot counter):
// all 16 members share one XCD L2 BY CONSTRUCTION.
//
// R12 = R7 skeleton + GUARDED fast-path poll (buffer_inv sc0), agent fallback.
//   Ledger: R5 1600 (atomicAdd+poll) | R6 3667 (agent-poll flood -> MALL traffic)
//   | R7 1452 (BEST: agent store-flag + wave0 throttled agent poll) | R8 94ms
//   (load `sc0` does NOT mean bypass-L1; it means workgroup-coherent => may be
//   served by stale L1) | R9 2251 (chain-multiplex serializes) | R10 3542
//   (poller count is the traffic knob) | R11 112ms (bare `buffer_inv` without
//   sc flags is a no-op for vL1 -> poll kept reading its own pinned L1 line).
//   Standing facts: (a) plain stores DO reach the XCD L2 (h-path correct in
//   every round incl. the two failures); (b) agent-scope ops round-trip the
//   MALL (~1.3us/step total sync cost - the R7 floor); (c) the HIP memory
//   model has no XCD scope, so an L2-local flag REQUIRES manual cache ops.
//   R12 hypothesis: `buffer_inv sc0` is the correct vL1-invalidate spelling
//   (gfx940+ cache ops select scope via sc flags; workgroup-acquire = sc0).
//   Poll round = buffer_inv sc0 -> vmcnt(0) -> plain global_load (must miss
//   the just-invalidated L1 -> served by the XCD L2 where producers' plain
//   write-through flag stores land). GUARD: only 8 fast rounds, then fall
//   back to R7's proven agent poll => worst case is R7+~2us/step, not 100x.
//   Arrival publishes BOTH: plain volatile store (L2 path) then agent atomic
//   store (backstop). Same value -> no consistency hazard.
//   Everything else byte-identical to R7.

#define BATCH  256
#define INPUT  128
#define HIDDEN 1024
#define OUTPUT 128
#define TSTEPS 512
#define NCAT   1152
#define NTILE  72
#define GROUPS 16
#define MEMB   16
#define NSLOT  4

// workspace layout (bytes)
#define WS_WFRAG 0u
#define WS_BEFF  2621440u
#define WS_HBUF  2629632u                 // 4 slots x 256x1024 f16 = 4x524288
#define WS_BAR   4726784u
// bar[] u32: [g*32 + mem]   per-member step flags (one 128B line per group)
//            [512 + xcc*32] per-XCD slot counters (one-time)
#define BAR_U32S 768

typedef _Float16 f16;
typedef _Float16 v8h __attribute__((ext_vector_type(8)));
typedef float    v4f __attribute__((ext_vector_type(4)));

__device__ __forceinline__ float fast_tanh(float x){
  float e = __expf(2.0f * x);
  return (e - 1.0f) / (e + 1.0f);
}

// Fast-path poll primitive: invalidate vL1 (sc0 = the workgroup-acquire
// spelling on gfx940+), then plain-load the flag word. The load must miss the
// just-invalidated L1 and is served by the XCD L2, where producers' plain
// write-through stores land. No sc1 anywhere => no MALL traffic.
__device__ __forceinline__ unsigned poll_flag_l2(const unsigned* p){
  unsigned v;
  asm volatile("buffer_inv sc0\n\t"
               "s_waitcnt vmcnt(0)\n\t"
               "global_load_dword %0, %1, off\n\t"
               "s_waitcnt vmcnt(0)"
               : "=v"(v) : "v"(p) : "memory");
  return v;
}

// ---- bias composition
__global__ void k_bias(const float* __restrict__ bi2h, const float* __restrict__ bh2h,
                       const float* __restrict__ bh2o, const float* __restrict__ Wi2h,
                       float* __restrict__ beff){
  int n = blockIdx.x*256 + threadIdx.x;
  if (n >= 1168) return;
  float v = 0.f;
  if (n < HIDDEN){
    v = bi2h[n] + bh2h[n];
    for (int j=0;j<INPUT;j++) v += bh2o[j]*Wi2h[j*HIDDEN + n];
  } else if (n < NCAT){
    v = bh2o[n - HIDDEN];
  }
  beff[n] = v;
}

// ---- h_1 = tanh(x0 @ W_i2h + b_i2h + b_h2h) -> slot 0
__global__ void k_h1(const float* __restrict__ x0, const float* __restrict__ Wi2h,
                     const float* __restrict__ bi2h, const float* __restrict__ bh2h,
                     f16* __restrict__ hbuf){
  int idx = blockIdx.x*256 + threadIdx.x;
  int m = idx >> 10, n = idx & 1023;
  float acc = bi2h[n] + bh2h[n];
  const float* xr = x0 + m*INPUT;
  for (int j=0;j<INPUT;j++) acc += xr[j]*Wi2h[j*HIDDEN + n];
  hbuf[idx] = (f16)fast_tanh(acc);
}

// ---- traj[0] = x_0
__global__ void k_copy0(const float* __restrict__ x0, float* __restrict__ out){
  int i = blockIdx.x*256 + threadIdx.x;
  out[i] = x0[i];
}

// ---- W fragment packing: [mem 16][wave 4][kk 8][c 5][lane 64][8 halves]
__global__ void k_wfrag(const float* __restrict__ Wh2h, const float* __restrict__ Wh2o,
                        const float* __restrict__ Wi2h, f16* __restrict__ Wfrag){
  int gid = blockIdx.x*256 + threadIdx.x;
  int lane = gid & 63;
  int fi = gid >> 6;
  int c = fi % 5, kk = (fi/5) & 7, wv = (fi/40) & 3, mem = fi/160;
  int k0 = wv*256 + kk*32 + (lane>>4)*8;
  int n  = mem*NTILE + c*16 + (lane & 15);
  f16 vals[8];
  if (n >= NCAT){
    #pragma unroll
    for (int j=0;j<8;j++) vals[j] = (f16)0.f;
  } else if (n >= HIDDEN){
    #pragma unroll
    for (int j=0;j<8;j++) vals[j] = (f16)Wh2o[(k0+j)*OUTPUT + (n-HIDDEN)];
  } else {
    float acc[8];
    #pragma unroll
    for (int j=0;j<8;j++) acc[j] = Wh2h[(k0+j)*HIDDEN + n];
    for (int q=0;q<INPUT;q++){
      float wi = Wi2h[q*HIDDEN + n];
      #pragma unroll
      for (int j=0;j<8;j++) acc[j] += Wh2o[(k0+j)*OUTPUT + q]*wi;
    }
    #pragma unroll
    for (int j=0;j<8;j++) vals[j] = (f16)acc[j];
  }
  v8h pack;
  #pragma unroll
  for (int j=0;j<8;j++) pack[j] = vals[j];
  *(v8h*)(Wfrag + (size_t)gid*8) = pack;
}

// ---- persistent recurrence kernel: 256 blocks x 256 threads, 1 block/CU (96KB dyn LDS)
__global__ void __launch_bounds__(256, 1)
k_rnn(const f16* __restrict__ Wfrag, const float* __restrict__ beff,
      f16* __restrict__ hbuf, unsigned int* __restrict__ bar,
      float* __restrict__ out){
  extern __shared__ char lds_raw[];
  float*    red    = (float*)lds_raw;              // [(c*3+rank)][lane][4] f32, 15360 B
  unsigned* s_slot = (unsigned*)(lds_raw + 16384);

  const int tid  = threadIdx.x;
  const int lane = tid & 63;
  const int wv   = tid >> 6;

  // Dynamic same-XCD group formation. 1 block/CU + grid==CU count => 32 blocks/XCD.
  // Group = xcc*2 + slot/16, member = slot%16: group shares one XCD L2 BY CONSTRUCTION.
  if (tid == 0){
    unsigned xcc;
    asm volatile("s_getreg_b32 %0, hwreg(HW_REG_XCC_ID)" : "=s"(xcc));
    xcc &= 7;
    unsigned slot = atomicAdd(&bar[512 + xcc*32], 1u);  // one-time, device-scope
    *s_slot = xcc*32 + (slot & 31u);
  }
  __syncthreads();
  const unsigned sid = *s_slot;
  const int g   = sid >> 4;
  const int mem = sid & 15;
  if (g >= GROUPS) return;
  const int m0   = g * 16;
  const int n0   = mem * NTILE;
  const int quad = lane >> 4;
  const int l15  = lane & 15;

  // B fragments resident in registers for the whole 511-step loop
  v8h bw[8][5];
  {
    const f16* wp = Wfrag + ((size_t)((mem*4 + wv)*40)*64 + lane)*8;
    #pragma unroll
    for (int kk=0;kk<8;kk++)
      #pragma unroll
      for (int c=0;c<5;c++)
        bw[kk][c] = *(const v8h*)(wp + (size_t)((kk*5+c)*64)*8);
  }

  // Per-thread bias for owned columns hoisted into registers (the per-step
  // beff[col] load always missed L1 — A-stream evicts it — and sat on the
  // post-reduce critical path). wv owns tiles c where c&3==wv.
  float bown[2] = {0.f, 0.f};
  #pragma unroll
  for (int c=0;c<5;c++){
    if ((c & 3) == wv){
      int colT = c*16 + l15;
      int col  = n0 + colT;
      if (colT < NTILE && col < NCAT) bown[c>>2] = beff[col];
    }
  }

  const int kbase = wv*256;
  unsigned int* flg = bar + g*32;   // 16 per-member flags, one 128B line per group

  for (int t=1; t<TSTEPS; ++t){
    // ---- wait: all 16 member flags >= t-1. Wave 0 ONLY (poller count is the
    // traffic knob — R6/R10).
    //   Fast path (8 rounds): buffer_inv sc0 + plain load = XCD-L2-served.
    //   Fallback: R7's proven agent poll (bounded). Worst case = R7 + ~2us/step.
    if (wv == 0){
      const unsigned target = (unsigned)(t-1);
      const unsigned* fp = flg + (lane & 15);
      bool done = false;
      #pragma unroll 1
      for (int i=0;i<8 && !done;i++){
        unsigned f = poll_flag_l2(fp);
        done = __all((int)(f >= target));
        if (!done) __builtin_amdgcn_s_sleep(1);
      }
      if (!done){
        unsigned tries = 0;
        for (;;){
          unsigned f = __hip_atomic_load(fp, __ATOMIC_RELAXED,
                                         __HIP_MEMORY_SCOPE_AGENT);
          if (__all((int)(f >= target))) break;
          if (++tries > 2048u) break;
          __builtin_amdgcn_s_sleep(1);
        }
      }
    }
    __syncthreads();   // release: waves 1-3 park here while wave 0 polls

    const f16* hin  = hbuf + (size_t)((t-1)&(NSLOT-1))*(BATCH*HIDDEN);
    f16*       hout = hbuf + (size_t)(t&(NSLOT-1))*(BATCH*HIDDEN);

    // A fragments: plain vector loads. 4-slot rotation guarantees the L1 line
    // for this address was evicted (128KB/step streamed) => miss L1, hit the
    // shared XCD L2 (always fresh). lane holds A[m=lane&15][k=quad*8+j].
    v8h af[8];
    {
      const v8h* abase = (const v8h*)(hin + (size_t)(m0 + l15)*HIDDEN + kbase + quad*8);
      #pragma unroll
      for (int kk=0;kk<8;kk++)
        af[kk] = abase[kk*4];            // stride 32 halves = 4 v8h
    }

    v4f acc[5];
    #pragma unroll
    for (int c=0;c<5;c++){ v4f z = {0.f,0.f,0.f,0.f}; acc[c] = z; }

    #pragma unroll
    for (int kk=0;kk<8;kk++){
      #pragma unroll
      for (int c=0;c<5;c++)
        acc[c] = __builtin_amdgcn_mfma_f32_16x16x32_f16(af[kk], bw[kk][c], acc[c], 0,0,0);
    }

    // cross-wave K reduction via LDS. tile c owner = c&3.
    #pragma unroll
    for (int c=0;c<5;c++){
      int owner = c & 3;
      if (wv != owner){
        int rank = (wv > owner) ? wv-1 : wv;
        *(v4f*)(red + ((size_t)(c*3 + rank)*64 + lane)*4) = acc[c];
      }
    }
    __syncthreads();   // reduce visibility

    // pass 1: hidden columns (consumed by the group next step) -> plain stores
    // into the XCD L2.
    #pragma unroll
    for (int c=0;c<5;c++){
      if ((c & 3) == wv){
        int colT = c*16 + l15;
        int col  = n0 + colT;
        if (col < HIDDEN && colT < NTILE){
          v4f s = acc[c];
          #pragma unroll
          for (int r=0;r<3;r++) s += *(const v4f*)(red + ((size_t)(c*3 + r)*64 + lane)*4);
          float b = bown[c>>2];
          #pragma unroll
          for (int r=0;r<4;r++){
            float v = fast_tanh(s[r] + b);
            hout[(size_t)(m0 + quad*4 + r)*HIDDEN + col] = (f16)v;  // C/D: col=lane&15,row=quad*4+r
          }
        }
      }
    }
    __syncthreads();   // drain: each wave waits vmcnt(0) => all h stores acked in L2

    // arrival: BOTH paths, same value.
    //   (1) plain volatile store -> write-through vL1 -> XCD L2 (fast path)
    //   (2) agent atomic store  -> MALL (R7-proven backstop for the fallback poll)
    // h-then-flag order guaranteed by the drain barrier's vmcnt(0).
    if (tid == 0){
      *(volatile unsigned*)(flg + mem) = (unsigned)t;
      __hip_atomic_store(flg + mem, (unsigned)t, __ATOMIC_RELAXED,
                         __HIP_MEMORY_SCOPE_AGENT);
    }

    // pass 2: y columns (consumed by nobody) — off the critical path, overlaps
    // group-mates' polling. red stable until next step's post-release writes.
    #pragma unroll
    for (int c=0;c<5;c++){
      if ((c & 3) == wv){
        int colT = c*16 + l15;
        int col  = n0 + colT;
        if (col >= HIDDEN && colT < NTILE){
          v4f s = acc[c];
          #pragma unroll
          for (int r=0;r<3;r++) s += *(const v4f*)(red + ((size_t)(c*3 + r)*64 + lane)*4);
          float b = bown[c>>2];
          float* op = out + (size_t)t*(BATCH*OUTPUT) + (col - HIDDEN);
          #pragma unroll
          for (int r=0;r<4;r++)
            op[(size_t)(m0 + quad*4 + r)*OUTPUT] = s[r] + b;
        }
      }
    }
  }
}

extern "C" void kernel_launch(void* const* d_in, const int* in_sizes, int n_in,
                              void* d_out, int out_size, void* d_ws, size_t ws_size,
                              hipStream_t stream){
  const float* x0   = (const float*)d_in[0];
  const float* Wi2h = (const float*)d_in[1];
  const float* bi2h = (const float*)d_in[2];
  const float* Wh2h = (const float*)d_in[3];
  const float* bh2h = (const float*)d_in[4];
  const float* Wh2o = (const float*)d_in[5];
  const float* bh2o = (const float*)d_in[6];
  float* out = (float*)d_out;
  char* ws = (char*)d_ws;

  f16*          Wfrag = (f16*)(ws + WS_WFRAG);
  float*        beff  = (float*)(ws + WS_BEFF);
  f16*          hbuf  = (f16*)(ws + WS_HBUF);
  unsigned int* bar   = (unsigned int*)(ws + WS_BAR);

  hipMemsetAsync(bar, 0, BAR_U32S*sizeof(unsigned int), stream);
  k_bias <<<5,    256, 0, stream>>>(bi2h, bh2h, bh2o, Wi2h, beff);
  k_h1   <<<1024, 256, 0, stream>>>(x0, Wi2h, bi2h, bh2h, hbuf);
  k_copy0<<<128,  256, 0, stream>>>(x0, out);
  k_wfrag<<<640,  256, 0, stream>>>(Wh2h, Wh2o, Wi2h, Wfrag);

  // 96KB dynamic LDS forces 1 block/CU -> all 256 blocks co-resident, 32 per XCD,
  // 1 wave/SIMD -> full VGPR budget for register-resident W fragments.
  hipFuncSetAttribute((const void*)k_rnn, hipFuncAttributeMaxDynamicSharedMemorySize, 98304);
  k_rnn<<<256, 256, 98304, stream>>>(Wfrag, beff, hbuf, bar, out);
}

// Round 8
// 1692.691 us; speedup vs baseline: 66.2669x; 1.1133x over previous
//
#include <hip/hip_runtime.h>
#include <cstdint>
#include <cstddef>

// PlainRNN fused: h_{t+1} = tanh(h_t @ W_eff + b_eff), traj[t] = h_t @ W_h2o + b_h2o
// W_eff = W_h2h + W_h2o @ W_i2h  (recurrence composition removes x from the loop)
//
// Persistent kernel: 16 groups (16 batch rows each) x 16 blocks (72 of 1152 cols).
// Groups formed DYNAMICALLY per-XCD (HW_REG_XCC_ID + per-XCD slot counter):
// all 16 members share one XCD L2 BY CONSTRUCTION.
//
// R13 = R7 + PER-WAVE SELF-RELEASE on producer subsets (no release barrier).
//   Ledger: R5 1600 | R6 3667 (64 per-wave agent stores + 4x unthrottled pollers
//   melted the MALL) | R7 1452 (BEST: 16 member flags, tid0 agent store, wave0
//   throttled agent poll) | R8 94ms, R11 112ms, R12 1884: three spellings of
//   "XCD-L2-local flag" all failed -> cross-CU flag visibility REQUIRES agent
//   scope; its ~1.0-1.3us RT is the sync mechanism's floor. | R9 2251 (chain
//   multiplex = serialization) | R10 3542 (per-wave agent stores + 4x pollers).
//   R13 idea: each wave's A-fragment (K-slice of 256 cols) depends on only
//   4-6 members (member m produces cols [72m,72m+72)): wv0 needs m0-3,
//   wv1 m3-7, wv2 m7-10, wv3 m10-14 (+15 as anti-lap guard). Each wave polls
//   ONLY its subset and self-releases: no release barrier, the straggler gates
//   only the wave that actually consumes its columns, other waves' af/MFMA
//   overlap the wait, and the af L2 bursts de-cluster.
//   Flag STORES stay exactly R7 (16/group, tid0, after drain barrier) — R6/R10
//   melts involved 64 per-wave agent stores; only poll-load traffic rises here
//   (4x R7 ~ half of R6's level), s_sleep backoff retained.
//   red[] becomes step-parity double-buffered (no release barrier => step t
//   pass2 reads could race a fast wave's step t+1 reduce writes).
//   Loop-end vmcnt(0): members 14/15's y-stores (HBM) otherwise linger in the
//   vmcnt queue and stall their NEXT step's af consumption (vmcnt counts all
//   VMEM ops in order); draining during the poll window is free.
//   h data unchanged: plain stores -> XCD L2; consumers plain-load + 4-slot
//   hbuf rotation (128KB/step streams the 32KB L1 -> always-fresh L2 hits).

#define BATCH  256
#define INPUT  128
#define HIDDEN 1024
#define OUTPUT 128
#define TSTEPS 512
#define NCAT   1152
#define NTILE  72
#define GROUPS 16
#define MEMB   16
#define NSLOT  4

// workspace layout (bytes)
#define WS_WFRAG 0u
#define WS_BEFF  2621440u
#define WS_HBUF  2629632u                 // 4 slots x 256x1024 f16 = 4x524288
#define WS_BAR   4726784u
// bar[] u32: [g*32 + mem]   per-member step flags (one 128B line per group)
//            [512 + xcc*32] per-XCD slot counters (one-time)
#define BAR_U32S 768

typedef _Float16 f16;
typedef _Float16 v8h __attribute__((ext_vector_type(8)));
typedef float    v4f __attribute__((ext_vector_type(4)));

__device__ __forceinline__ float fast_tanh(float x){
  float e = __expf(2.0f * x);
  return (e - 1.0f) / (e + 1.0f);
}

// ---- bias composition
__global__ void k_bias(const float* __restrict__ bi2h, const float* __restrict__ bh2h,
                       const float* __restrict__ bh2o, const float* __restrict__ Wi2h,
                       float* __restrict__ beff){
  int n = blockIdx.x*256 + threadIdx.x;
  if (n >= 1168) return;
  float v = 0.f;
  if (n < HIDDEN){
    v = bi2h[n] + bh2h[n];
    for (int j=0;j<INPUT;j++) v += bh2o[j]*Wi2h[j*HIDDEN + n];
  } else if (n < NCAT){
    v = bh2o[n - HIDDEN];
  }
  beff[n] = v;
}

// ---- h_1 = tanh(x0 @ W_i2h + b_i2h + b_h2h) -> slot 0
__global__ void k_h1(const float* __restrict__ x0, const float* __restrict__ Wi2h,
                     const float* __restrict__ bi2h, const float* __restrict__ bh2h,
                     f16* __restrict__ hbuf){
  int idx = blockIdx.x*256 + threadIdx.x;
  int m = idx >> 10, n = idx & 1023;
  float acc = bi2h[n] + bh2h[n];
  const float* xr = x0 + m*INPUT;
  for (int j=0;j<INPUT;j++) acc += xr[j]*Wi2h[j*HIDDEN + n];
  hbuf[idx] = (f16)fast_tanh(acc);
}

// ---- traj[0] = x_0
__global__ void k_copy0(const float* __restrict__ x0, float* __restrict__ out){
  int i = blockIdx.x*256 + threadIdx.x;
  out[i] = x0[i];
}

// ---- W fragment packing: [mem 16][wave 4][kk 8][c 5][lane 64][8 halves]
__global__ void k_wfrag(const float* __restrict__ Wh2h, const float* __restrict__ Wh2o,
                        const float* __restrict__ Wi2h, f16* __restrict__ Wfrag){
  int gid = blockIdx.x*256 + threadIdx.x;
  int lane = gid & 63;
  int fi = gid >> 6;
  int c = fi % 5, kk = (fi/5) & 7, wv = (fi/40) & 3, mem = fi/160;
  int k0 = wv*256 + kk*32 + (lane>>4)*8;
  int n  = mem*NTILE + c*16 + (lane & 15);
  f16 vals[8];
  if (n >= NCAT){
    #pragma unroll
    for (int j=0;j<8;j++) vals[j] = (f16)0.f;
  } else if (n >= HIDDEN){
    #pragma unroll
    for (int j=0;j<8;j++) vals[j] = (f16)Wh2o[(k0+j)*OUTPUT + (n-HIDDEN)];
  } else {
    float acc[8];
    #pragma unroll
    for (int j=0;j<8;j++) acc[j] = Wh2h[(k0+j)*HIDDEN + n];
    for (int q=0;q<INPUT;q++){
      float wi = Wi2h[q*HIDDEN + n];
      #pragma unroll
      for (int j=0;j<8;j++) acc[j] += Wh2o[(k0+j)*OUTPUT + q]*wi;
    }
    #pragma unroll
    for (int j=0;j<8;j++) vals[j] = (f16)acc[j];
  }
  v8h pack;
  #pragma unroll
  for (int j=0;j<8;j++) pack[j] = vals[j];
  *(v8h*)(Wfrag + (size_t)gid*8) = pack;
}

// ---- persistent recurrence kernel: 256 blocks x 256 threads, 1 block/CU (96KB dyn LDS)
__global__ void __launch_bounds__(256, 1)
k_rnn(const f16* __restrict__ Wfrag, const float* __restrict__ beff,
      f16* __restrict__ hbuf, unsigned int* __restrict__ bar,
      float* __restrict__ out){
  extern __shared__ char lds_raw[];
  // red: step-parity double buffer at +0 / +16384 (15360 B used each).
  unsigned* s_slot = (unsigned*)(lds_raw + 32768);

  const int tid  = threadIdx.x;
  const int lane = tid & 63;
  const int wv   = tid >> 6;

  // Dynamic same-XCD group formation. 1 block/CU + grid==CU count => 32 blocks/XCD.
  // Group = xcc*2 + slot/16, member = slot%16: group shares one XCD L2 BY CONSTRUCTION.
  if (tid == 0){
    unsigned xcc;
    asm volatile("s_getreg_b32 %0, hwreg(HW_REG_XCC_ID)" : "=s"(xcc));
    xcc &= 7;
    unsigned slot = atomicAdd(&bar[512 + xcc*32], 1u);  // one-time, device-scope
    *s_slot = xcc*32 + (slot & 31u);
  }
  __syncthreads();
  const unsigned sid = *s_slot;
  const int g   = sid >> 4;
  const int mem = sid & 15;
  if (g >= GROUPS) return;
  const int m0   = g * 16;
  const int n0   = mem * NTILE;
  const int quad = lane >> 4;
  const int l15  = lane & 15;

  // B fragments resident in registers for the whole 511-step loop
  v8h bw[8][5];
  {
    const f16* wp = Wfrag + ((size_t)((mem*4 + wv)*40)*64 + lane)*8;
    #pragma unroll
    for (int kk=0;kk<8;kk++)
      #pragma unroll
      for (int c=0;c<5;c++)
        bw[kk][c] = *(const v8h*)(wp + (size_t)((kk*5+c)*64)*8);
  }

  // Bias hoisted to registers (the per-step beff load always missed L1 — the
  // A-stream evicts it — and sat on the post-reduce critical path).
  float bown[2] = {0.f, 0.f};
  #pragma unroll
  for (int c=0;c<5;c++){
    if ((c & 3) == wv){
      int colT = c*16 + l15;
      int col  = n0 + colT;
      if (colT < NTILE && col < NCAT) bown[c>>2] = beff[col];
    }
  }

  const int kbase = wv*256;
  unsigned int* flg = bar + g*32;   // 16 per-member flags, one 128B line per group

  // Producer subset for THIS wave's K-slice [kbase, kbase+256):
  // member m produces h cols [72m, 72m+72). wv0:0-3 wv1:3-7 wv2:7-10 wv3:10-14.
  // wv3 additionally gates member 15 (pure-y member, flags early): keeps every
  // member inside someone's poll set => nobody can be lapped past the 4-slot
  // hbuf rotation's slack.
  int plo = (wv*256) / NTILE;
  int phi = (wv*256 + 255) / NTILE;
  if (wv == 3) phi = MEMB - 1;
  const int span = phi - plo + 1;                 // 4,5,4,6
  int pm = plo + (lane & 7);
  const int pdontcare = ((lane & 7) >= span) ? 1 : 0;
  if (pm > phi) pm = phi;
  const unsigned* fpoll = flg + pm;

  for (int t=1; t<TSTEPS; ++t){
    // ---- self-release: EACH wave polls only its producer subset (same single
    // 128B line; agent-relaxed loads; s_sleep backoff). No release barrier —
    // a wave starts its af loads the moment ITS producers are done. The group
    // straggler gates only the wave that consumes its columns.
    // Bounded: broken sync degrades to timeout (visible absmax/dur), no hang.
    {
      const unsigned target = (unsigned)(t-1);
      unsigned tries = 0;
      for (;;){
        unsigned f = __hip_atomic_load(fpoll, __ATOMIC_RELAXED,
                                       __HIP_MEMORY_SCOPE_AGENT);
        if (__all((int)((f >= target) || pdontcare))) break;
        if (++tries > 2048u) break;
        __builtin_amdgcn_s_sleep(1);
      }
    }

    const f16* hin  = hbuf + (size_t)((t-1)&(NSLOT-1))*(BATCH*HIDDEN);
    f16*       hout = hbuf + (size_t)(t&(NSLOT-1))*(BATCH*HIDDEN);
    float*     red  = (float*)(lds_raw + (size_t)(t & 1)*16384);

    // A fragments: plain vector loads. 4-slot rotation guarantees the L1 line
    // for this address was evicted (128KB/step streamed) => miss L1, hit the
    // shared XCD L2 (always fresh). lane holds A[m=lane&15][k=quad*8+j].
    v8h af[8];
    {
      const v8h* abase = (const v8h*)(hin + (size_t)(m0 + l15)*HIDDEN + kbase + quad*8);
      #pragma unroll
      for (int kk=0;kk<8;kk++)
        af[kk] = abase[kk*4];            // stride 32 halves = 4 v8h
    }

    v4f acc[5];
    #pragma unroll
    for (int c=0;c<5;c++){ v4f z = {0.f,0.f,0.f,0.f}; acc[c] = z; }

    #pragma unroll
    for (int kk=0;kk<8;kk++){
      #pragma unroll
      for (int c=0;c<5;c++)
        acc[c] = __builtin_amdgcn_mfma_f32_16x16x32_f16(af[kk], bw[kk][c], acc[c], 0,0,0);
    }

    // cross-wave K reduction via LDS (parity buffer). tile c owner = c&3.
    #pragma unroll
    for (int c=0;c<5;c++){
      int owner = c & 3;
      if (wv != owner){
        int rank = (wv > owner) ? wv-1 : wv;
        *(v4f*)(red + ((size_t)(c*3 + rank)*64 + lane)*4) = acc[c];
      }
    }
    __syncthreads();   // reduce visibility (re-syncs the self-released waves)

    // pass 1: hidden columns (consumed by the group next step) -> plain stores
    // into the XCD L2.
    #pragma unroll
    for (int c=0;c<5;c++){
      if ((c & 3) == wv){
        int colT = c*16 + l15;
        int col  = n0 + colT;
        if (col < HIDDEN && colT < NTILE){
          v4f s = acc[c];
          #pragma unroll
          for (int r=0;r<3;r++) s += *(const v4f*)(red + ((size_t)(c*3 + r)*64 + lane)*4);
          float b = bown[c>>2];
          #pragma unroll
          for (int r=0;r<4;r++){
            float v = fast_tanh(s[r] + b);
            hout[(size_t)(m0 + quad*4 + r)*HIDDEN + col] = (f16)v;  // C/D: col=lane&15,row=quad*4+r
          }
        }
      }
    }
    __syncthreads();   // drain: each wave waits vmcnt(0) => all h stores acked in L2

    // arrival: ONE agent-relaxed store per member (R7-proven form & traffic).
    // h-then-flag order guaranteed by the drain barrier's vmcnt(0).
    if (tid == 0)
      __hip_atomic_store(flg + mem, (unsigned)t, __ATOMIC_RELAXED,
                         __HIP_MEMORY_SCOPE_AGENT);

    // pass 2: y columns (consumed by nobody) — off the critical path, overlaps
    // group-mates' polling. red[t&1] stable until t+2 (parity).
    #pragma unroll
    for (int c=0;c<5;c++){
      if ((c & 3) == wv){
        int colT = c*16 + l15;
        int col  = n0 + colT;
        if (col >= HIDDEN && colT < NTILE){
          v4f s = acc[c];
          #pragma unroll
          for (int r=0;r<3;r++) s += *(const v4f*)(red + ((size_t)(c*3 + r)*64 + lane)*4);
          float b = bown[c>>2];
          float* op = out + (size_t)t*(BATCH*OUTPUT) + (col - HIDDEN);
          #pragma unroll
          for (int r=0;r<4;r++)
            op[(size_t)(m0 + quad*4 + r)*OUTPUT] = s[r] + b;
        }
      }
    }

    // drain y/flag stores NOW (during the poll window, off the critical path)
    // so next step's af-consumption vmcnt doesn't inherit slow HBM store acks
    // (vmcnt counts loads AND stores in issue order).
    asm volatile("s_waitcnt vmcnt(0)" ::: "memory");
  }
}

extern "C" void kernel_launch(void* const* d_in, const int* in_sizes, int n_in,
                              void* d_out, int out_size, void* d_ws, size_t ws_size,
                              hipStream_t stream){
  const float* x0   = (const float*)d_in[0];
  const float* Wi2h = (const float*)d_in[1];
  const float* bi2h = (const float*)d_in[2];
  const float* Wh2h = (const float*)d_in[3];
  const float* bh2h = (const float*)d_in[4];
  const float* Wh2o = (const float*)d_in[5];
  const float* bh2o = (const float*)d_in[6];
  float* out = (float*)d_out;
  char* ws = (char*)d_ws;

  f16*          Wfrag = (f16*)(ws + WS_WFRAG);
  float*        beff  = (float*)(ws + WS_BEFF);
  f16*          hbuf  = (f16*)(ws + WS_HBUF);
  unsigned int* bar   = (unsigned int*)(ws + WS_BAR);

  hipMemsetAsync(bar, 0, BAR_U32S*sizeof(unsigned int), stream);
  k_bias <<<5,    256, 0, stream>>>(bi2h, bh2h, bh2o, Wi2h, beff);
  k_h1   <<<1024, 256, 0, stream>>>(x0, Wi2h, bi2h, bh2h, hbuf);
  k_copy0<<<128,  256, 0, stream>>>(x0, out);
  k_wfrag<<<640,  256, 0, stream>>>(Wh2h, Wh2o, Wi2h, Wfrag);

  // 96KB dynamic LDS forces 1 block/CU -> all 256 blocks co-resident, 32 per XCD,
  // 1 wave/SIMD -> full VGPR budget for register-resident W fragments.
  hipFuncSetAttribute((const void*)k_rnn, hipFuncAttributeMaxDynamicSharedMemorySize, 98304);
  k_rnn<<<256, 256, 98304, stream>>>(Wfrag, beff, hbuf, bar, out);
}